// Round 5
// baseline (325.403 us; speedup 1.0000x reference)
//
#include <hip/hip_runtime.h>
#include <hip/hip_bf16.h>

#define PB   512   // edge-stripe blocks for bucket scatter
#define BN   64    // nodes per bucket
#define CAP  1344  // per-bucket capacity (Poisson(1024), sigma 32 -> 10 sigma slack)

typedef short bf16x8 __attribute__((ext_vector_type(8)));
typedef float f32x4  __attribute__((ext_vector_type(4)));

__device__ __forceinline__ unsigned short f2bf(float f) {  // RNE f32->bf16
    unsigned u = __float_as_uint(f);
    u += 0x7FFFu + ((u >> 16) & 1u);
    return (unsigned short)(u >> 16);
}

// ============ merged: CSR pass 1 (bucketize) + weight packs + bf16 shadow of x ========
// (byte-identical to r3's build: bucket-64, interleaved xb -- 54.6us measured.)
// blocks [0,PB):        edge-stripe bucketize with atomic reservation
// blocks [PB,PB+96):    pack bw[w][...] per MFMA B-frag swizzle
// blocks [PB+96, ...):  f32 -> bf16 copy of x, INTERLEAVED xb[n][64] -- r4 proved
//                       the interleaved row is line-optimal (1 L2 line/edge);
//                       split halves doubled lines/edge (FETCH 86->122MB). 
__global__ __launch_bounds__(256) void build_and_prep(
        const int* __restrict__ src, const int* __restrict__ dst,
        int* __restrict__ gcount, int* __restrict__ pairs, int E, int NB,
        const float* __restrict__ x, unsigned short* __restrict__ xb, int n8,
        const float* __restrict__ Ws1, const float* __restrict__ Wn1,
        const float* __restrict__ Ws2, const float* __restrict__ Wn2,
        const float* __restrict__ Ws3, const float* __restrict__ Wn3,
        unsigned short* __restrict__ bw) {
    const int tid = threadIdx.x;
    if (blockIdx.x < PB) {
        __shared__ int h[1664];
        for (int i = tid; i < NB; i += 256) h[i] = 0;
        __syncthreads();
        const int per = (E + PB - 1) / PB;
        const int s = blockIdx.x * per;
        const int e = min(E, s + per);
        for (int i = s + tid; i < e; i += 256) atomicAdd(&h[dst[i] >> 6], 1);
        __syncthreads();
        for (int b = tid; b < NB; b += 256) {
            const int c = h[b];
            h[b] = (c > 0) ? atomicAdd(&gcount[b], c) : 0;  // bucket-local base of this block's run
        }
        __syncthreads();
        for (int i = s + tid; i < e; i += 256) {
            const int d = dst[i];
            const int b = d >> 6;
            const int slot = atomicAdd(&h[b], 1);           // bucket-local slot
            if (slot < CAP)
                pairs[(size_t)b * CAP + slot] = src[i] | ((d & 63) << 20);
        }
    } else if (blockIdx.x < PB + 96) {
        // ---- weight packs: bw[((s*4+t)*64 + lane)*8 + j] =
        //        B[s*32 + (lane>>4)*8 + j][t*16 + (lane&15)]
        const int i = (blockIdx.x - PB) * 256 + tid;  // 0..24575
        const int w = i >> 13;
        const int r = i & 8191;
        const float* Ws = (w == 0) ? Ws1 : (w == 1) ? Ws2 : Ws3;
        const float* Wn = (w == 0) ? Wn1 : (w == 1) ? Wn2 : Wn3;
        const int j = r & 7;
        const int L = (r >> 3) & 63;
        const int t = (r >> 9) & 3;
        const int s = r >> 11;
        const int k = s * 32 + ((L >> 4) << 3) + j;
        const int n = t * 16 + (L & 15);
        const float v = (k < 64) ? Ws[k * 64 + n] : Wn[(k - 64) * 64 + n];
        bw[i] = f2bf(v);
    } else {
        const int g = (blockIdx.x - PB - 96) * 256 + tid;
        if (g >= n8) return;
        const float4 v0 = *(const float4*)(x + (size_t)g * 8);
        const float4 v1 = *(const float4*)(x + (size_t)g * 8 + 4);
        uint4 o;
        o.x = (unsigned)f2bf(v0.x) | ((unsigned)f2bf(v0.y) << 16);
        o.y = (unsigned)f2bf(v0.z) | ((unsigned)f2bf(v0.w) << 16);
        o.z = (unsigned)f2bf(v1.x) | ((unsigned)f2bf(v1.y) << 16);
        o.w = (unsigned)f2bf(v1.z) | ((unsigned)f2bf(v1.w) << 16);
        *(uint4*)(xb + (size_t)g * 8) = o;
    }
}

// ============ CSR pass 2: ONE WAVE per bucket, lane = node ============
// Replaces the 256-thread barrier/scan/atomic finalize (~27us): 64 lanes own
// the bucket's 64 nodes. Stage pairs to LDS + LDS-hist during the coalesced
// load; 6-step shfl_up wave prefix (no barriers, no scan loop, no cross-lane
// scatter atomics); then each lane serially extracts its node's edges with a
// private cursor -- per-row writes are sequential, whole bucket region dense.
__global__ __launch_bounds__(64) void csr_wave_finalize(
        const int* __restrict__ pairs, const int* __restrict__ gcount,
        int2* __restrict__ rowrange, int* __restrict__ col, int N) {
    __shared__ int sp[CAP];
    __shared__ int h[BN];
    const int lane = threadIdx.x;   // 0..63
    const int b = blockIdx.x;
    const size_t base = (size_t)b * CAP;
    const int cnt = min(gcount[b], (int)CAP);

    h[lane] = 0;
    __syncthreads();
    for (int i = lane; i < cnt; i += 64) {
        const int p = pairs[base + i];
        sp[i] = p;
        atomicAdd(&h[(p >> 20) & 63], 1);
    }
    __syncthreads();

    const int deg = h[lane];
    int pre = deg;                   // inclusive prefix over 64 lanes
#pragma unroll
    for (int off = 1; off < 64; off <<= 1) {
        const int t = __shfl_up(pre, off, 64);
        if (lane >= off) pre += t;
    }
    const int excl = pre - deg;
    const int node = (b << 6) + lane;
    if (node < N)
        rowrange[node] = make_int2((int)base + excl, (int)base + excl + deg);

    int cur = (int)base + excl;      // private cursor, no atomics
    for (int i = 0; i < cnt; ++i) {
        const int p = sp[i];         // uniform address: LDS broadcast
        if (((p >> 20) & 63) == lane)
            col[cur++] = p & 0xFFFFF;
    }
}

// ============ fused layer: gather-mean + MFMA update (exact r1, 41.7us) ============
// 32 nodes/block, 128 threads (2 waves).
// Phase 1: 4 lanes/node, lane owns two contiguous 16B chunks (bytes [o*2,+16)
//   and [o*2+64,+16), o=(tid&3)*8): each vmem instruction's 4-lane group hits
//   exactly one 64B line. 4-edge unroll -> 8 outstanding loads/lane.
// Phase 2: wave w -> nodes node0+w*16..+15; A-frags: self rows from global,
//   mean from LDS; B-frags from pre-swizzled global bswp (L1-resident).
// outb MUST NOT alias xin (random neighbor reads).
#define ACC8U(A, V)                                                   \
    A[0] += __uint_as_float((V).x << 16);                             \
    A[1] += __uint_as_float((V).x & 0xFFFF0000u);                     \
    A[2] += __uint_as_float((V).y << 16);                             \
    A[3] += __uint_as_float((V).y & 0xFFFF0000u);                     \
    A[4] += __uint_as_float((V).z << 16);                             \
    A[5] += __uint_as_float((V).z & 0xFFFF0000u);                     \
    A[6] += __uint_as_float((V).w << 16);                             \
    A[7] += __uint_as_float((V).w & 0xFFFF0000u);

__global__ __launch_bounds__(128) void sage_fused_kernel(
        const unsigned short* __restrict__ xin, const int* __restrict__ col,
        const int2* __restrict__ rowrange,
        const unsigned short* __restrict__ bswp, const float* __restrict__ bias,
        unsigned short* __restrict__ outb,   // may be null; must not alias xin
        float* __restrict__ outf,            // may be null
        int N, int do_relu) {
    __shared__ __align__(16) unsigned short smean[32][72];

    const int tid = threadIdx.x;
    const int node0 = blockIdx.x * 32;
    const int lane = tid & 63;

    // ---- phase 1: gather mean for node (tid>>2), 32 B per lane ----
    {
        const int nl = tid >> 2;             // 0..31
        const int node = node0 + nl;
        const int o = (tid & 3) * 8;         // short offset: 0,8,16,24 (chunks o, o+32)
        float accA[8] = {0.f}, accB[8] = {0.f};
        float accC[8] = {0.f}, accD[8] = {0.f};
        float rd = 0.f;
        if (node < N) {
            const int2 rr = rowrange[node];
            const int beg = rr.x;
            const int end = rr.y;
            int i = beg;
            for (; i + 4 <= end; i += 4) {
                const int s0 = col[i + 0];
                const int s1 = col[i + 1];
                const int s2 = col[i + 2];
                const int s3 = col[i + 3];
                const unsigned short* p0 = xin + (size_t)s0 * 64 + o;
                const unsigned short* p1 = xin + (size_t)s1 * 64 + o;
                const unsigned short* p2 = xin + (size_t)s2 * 64 + o;
                const unsigned short* p3 = xin + (size_t)s3 * 64 + o;
                const uint4 a0 = *(const uint4*)(p0);
                const uint4 b0 = *(const uint4*)(p0 + 32);
                const uint4 a1 = *(const uint4*)(p1);
                const uint4 b1 = *(const uint4*)(p1 + 32);
                const uint4 a2 = *(const uint4*)(p2);
                const uint4 b2 = *(const uint4*)(p2 + 32);
                const uint4 a3 = *(const uint4*)(p3);
                const uint4 b3 = *(const uint4*)(p3 + 32);
                ACC8U(accA, a0) ACC8U(accB, b0)
                ACC8U(accC, a1) ACC8U(accD, b1)
                ACC8U(accA, a2) ACC8U(accB, b2)
                ACC8U(accC, a3) ACC8U(accD, b3)
            }
            for (; i < end; ++i) {
                const unsigned short* p = xin + (size_t)col[i] * 64 + o;
                const uint4 a = *(const uint4*)(p);
                const uint4 b = *(const uint4*)(p + 32);
                ACC8U(accA, a) ACC8U(accB, b)
            }
            rd = 1.0f / fmaxf((float)(end - beg), 1.0f);
        }
        uint4 o0, o1;
        {
            float m[8];
#pragma unroll
            for (int k = 0; k < 8; ++k) m[k] = (accA[k] + accC[k]) * rd;
            o0.x = (unsigned)f2bf(m[0]) | ((unsigned)f2bf(m[1]) << 16);
            o0.y = (unsigned)f2bf(m[2]) | ((unsigned)f2bf(m[3]) << 16);
            o0.z = (unsigned)f2bf(m[4]) | ((unsigned)f2bf(m[5]) << 16);
            o0.w = (unsigned)f2bf(m[6]) | ((unsigned)f2bf(m[7]) << 16);
#pragma unroll
            for (int k = 0; k < 8; ++k) m[k] = (accB[k] + accD[k]) * rd;
            o1.x = (unsigned)f2bf(m[0]) | ((unsigned)f2bf(m[1]) << 16);
            o1.y = (unsigned)f2bf(m[2]) | ((unsigned)f2bf(m[3]) << 16);
            o1.z = (unsigned)f2bf(m[4]) | ((unsigned)f2bf(m[5]) << 16);
            o1.w = (unsigned)f2bf(m[6]) | ((unsigned)f2bf(m[7]) << 16);
        }
        *(uint4*)(&smean[nl][o])      = o0;
        *(uint4*)(&smean[nl][o + 32]) = o1;
    }
    __syncthreads();

    // ---- phase 2: MFMA update (2 waves x 16 nodes) ----
    const int wave = tid >> 6;
    const int m    = lane & 15;
    const int quad = lane >> 4;
    const int nw0  = node0 + wave * 16;

    int arow = nw0 + m;
    if (arow >= N) arow = N - 1;             // clamp; stores are guarded
    const unsigned short* xr = xin + (size_t)arow * 64 + quad * 8;

    f32x4 acc[4];
#pragma unroll
    for (int t = 0; t < 4; ++t) {
        const float b = bias[t * 16 + m];
        acc[t] = (f32x4){b, b, b, b};
    }

#pragma unroll
    for (int s = 0; s < 4; ++s) {
        bf16x8 a;
        if (s < 2) a = *(const bf16x8*)(xr + s * 32);
        else       a = *(const bf16x8*)(&smean[wave * 16 + m][(s - 2) * 32 + quad * 8]);
#pragma unroll
        for (int t = 0; t < 4; ++t) {
            const bf16x8 bf = *(const bf16x8*)(bswp + (((s * 4 + t) * 64 + lane) << 3));
            acc[t] = __builtin_amdgcn_mfma_f32_16x16x32_bf16(a, bf, acc[t], 0, 0, 0);
        }
    }

    // C/D: col = t*16 + m, row(node) = nw0 + quad*4 + r
#pragma unroll
    for (int t = 0; t < 4; ++t) {
        const int colg = t * 16 + m;
#pragma unroll
        for (int r = 0; r < 4; ++r) {
            const int node = nw0 + quad * 4 + r;
            if (node < N) {
                float v = acc[t][r];
                if (do_relu) v = fmaxf(v, 0.f);
                if (outf) outf[(size_t)node * 64 + colg] = v;
                if (outb) outb[(size_t)node * 64 + colg] = f2bf(v);
            }
        }
    }
}

extern "C" void kernel_launch(void* const* d_in, const int* in_sizes, int n_in,
                              void* d_out, int out_size, void* d_ws, size_t ws_size,
                              hipStream_t stream) {
    const float* x   = (const float*)d_in[0];
    const int*   ei  = (const int*)d_in[1];
    const float* ws1 = (const float*)d_in[2];
    const float* wn1 = (const float*)d_in[3];
    const float* b1  = (const float*)d_in[4];
    const float* ws2 = (const float*)d_in[5];
    const float* wn2 = (const float*)d_in[6];
    const float* b2  = (const float*)d_in[7];
    const float* ws3 = (const float*)d_in[8];
    const float* wn3 = (const float*)d_in[9];
    const float* b3  = (const float*)d_in[10];

    const int N = in_sizes[0] / 64;   // 100000
    const int E = in_sizes[1] / 2;    // 1600000
    const int* src = ei;
    const int* dst = ei + E;
    const int NB = (N + BN - 1) / BN; // 1563 buckets of 64 nodes

    float* out = (float*)d_out;

    auto align256 = [](size_t v) { return (v + 255) / 256 * 256; };
    char* p = (char*)d_ws;
    int*  gcount   = (int*)p;  p += align256((size_t)NB * 4);
    int*  pairs    = (int*)p;  p += align256((size_t)NB * CAP * 4);
    int*  col      = (int*)p;  p += align256((size_t)NB * CAP * 4);
    int2* rowrange = (int2*)p; p += align256((size_t)N * 8);
    unsigned short* xb  = (unsigned short*)p; p += align256((size_t)N * 64 * 2);
    unsigned short* xb2 = (unsigned short*)p; p += align256((size_t)N * 64 * 2);
    unsigned short* bw  = (unsigned short*)p; p += align256(3 * 8192 * 2);

    const int n8 = N * 64 / 8;                            // 800000
    const int merged_blocks = PB + 96 + (n8 + 255) / 256; // 512 + 96 + 3125
    const int fused_blocks = (N + 31) / 32;               // 3125

    // ---- CSR pass 1 + weight packs + bf16 shadow, one launch ----
    hipMemsetAsync(gcount, 0, (size_t)NB * 4, stream);
    build_and_prep<<<merged_blocks, 256, 0, stream>>>(src, dst, gcount, pairs, E, NB,
                                                      x, xb, n8,
                                                      ws1, wn1, ws2, wn2, ws3, wn3, bw);
    // ---- CSR pass 2: one wave per bucket ----
    csr_wave_finalize<<<NB, 64, 0, stream>>>(pairs, gcount, rowrange, col, N);

    // ---- 3 fused layers (ping-pong xb <-> xb2) ----
    sage_fused_kernel<<<fused_blocks, 128, 0, stream>>>(xb,  col, rowrange, bw,         b1, xb2,     nullptr, N, 1);
    sage_fused_kernel<<<fused_blocks, 128, 0, stream>>>(xb2, col, rowrange, bw + 8192,  b2, xb,      nullptr, N, 1);
    sage_fused_kernel<<<fused_blocks, 128, 0, stream>>>(xb,  col, rowrange, bw + 16384, b3, nullptr, out,     N, 0);
}

// Round 6
// 263.918 us; speedup vs baseline: 1.2330x; 1.2330x over previous
//
#include <hip/hip_runtime.h>
#include <hip/hip_bf16.h>

#define PB   512   // edge-stripe blocks for bucket scatter
#define BN   64    // nodes per bucket
#define CAP  1344  // per-bucket capacity (Poisson(1024), sigma 32 -> 10 sigma slack)

typedef short bf16x8 __attribute__((ext_vector_type(8)));
typedef float f32x4  __attribute__((ext_vector_type(4)));

__device__ __forceinline__ unsigned short f2bf(float f) {  // RNE f32->bf16
    unsigned u = __float_as_uint(f);
    u += 0x7FFFu + ((u >> 16) & 1u);
    return (unsigned short)(u >> 16);
}

// int8 dequant-accumulate: 4 bytes of dword w scaled by s into A[i0..i0+3]
#define ACCB(A, i0, w, s)                                                \
    A[i0 + 0] = fmaf((float)(((int)((w) << 24)) >> 24), s, A[i0 + 0]);   \
    A[i0 + 1] = fmaf((float)(((int)((w) << 16)) >> 24), s, A[i0 + 1]);   \
    A[i0 + 2] = fmaf((float)(((int)((w) <<  8)) >> 24), s, A[i0 + 2]);   \
    A[i0 + 3] = fmaf((float)(((int)(w)) >> 24),         s, A[i0 + 3]);
#define ACCQ4(A, V, s) { ACCB(A, 0, (V).x, s) ACCB(A, 4, (V).y, s) ACCB(A, 8, (V).z, s) ACCB(A, 12, (V).w, s) }

// ============ merged: CSR pass 1 (bucketize) + weight packs + x shadows ============
// blocks [0,PB):        edge-stripe bucketize with atomic reservation (r3 form)
// blocks [PB,PB+96):    pack bw[w][...] per MFMA B-frag swizzle
// blocks [PB+96, ...):  x -> bf16 xb (self path, exact) AND int8+scale xq/xs
//                       (gather path: row = 64B = ONE cache line; random-gather
//                       footprint 12.8 -> 6.4 MB). Per-row symmetric absmax/127.
__global__ __launch_bounds__(256) void build_and_prep(
        const int* __restrict__ src, const int* __restrict__ dst,
        int* __restrict__ gcount, int* __restrict__ pairs, int E, int NB,
        const float* __restrict__ x, unsigned short* __restrict__ xb,
        unsigned char* __restrict__ xq, float* __restrict__ xs, int n8,
        const float* __restrict__ Ws1, const float* __restrict__ Wn1,
        const float* __restrict__ Ws2, const float* __restrict__ Wn2,
        const float* __restrict__ Ws3, const float* __restrict__ Wn3,
        unsigned short* __restrict__ bw) {
    const int tid = threadIdx.x;
    if (blockIdx.x < PB) {
        __shared__ int h[1664];
        for (int i = tid; i < NB; i += 256) h[i] = 0;
        __syncthreads();
        const int per = (E + PB - 1) / PB;
        const int s = blockIdx.x * per;
        const int e = min(E, s + per);
        for (int i = s + tid; i < e; i += 256) atomicAdd(&h[dst[i] >> 6], 1);
        __syncthreads();
        for (int b = tid; b < NB; b += 256) {
            const int c = h[b];
            h[b] = (c > 0) ? atomicAdd(&gcount[b], c) : 0;  // bucket-local base of this block's run
        }
        __syncthreads();
        for (int i = s + tid; i < e; i += 256) {
            const int d = dst[i];
            const int b = d >> 6;
            const int slot = atomicAdd(&h[b], 1);           // bucket-local slot
            if (slot < CAP)
                pairs[(size_t)b * CAP + slot] = src[i] | ((d & 63) << 20);
        }
    } else if (blockIdx.x < PB + 96) {
        // ---- weight packs: bw[((s*4+t)*64 + lane)*8 + j] =
        //        B[s*32 + (lane>>4)*8 + j][t*16 + (lane&15)]
        const int i = (blockIdx.x - PB) * 256 + tid;  // 0..24575
        const int w = i >> 13;
        const int r = i & 8191;
        const float* Ws = (w == 0) ? Ws1 : (w == 1) ? Ws2 : Ws3;
        const float* Wn = (w == 0) ? Wn1 : (w == 1) ? Wn2 : Wn3;
        const int j = r & 7;
        const int L = (r >> 3) & 63;
        const int t = (r >> 9) & 3;
        const int s = r >> 11;
        const int k = s * 32 + ((L >> 4) << 3) + j;
        const int n = t * 16 + (L & 15);
        const float v = (k < 64) ? Ws[k * 64 + n] : Wn[(k - 64) * 64 + n];
        bw[i] = f2bf(v);
    } else {
        const int g = (blockIdx.x - PB - 96) * 256 + tid;   // exact grid, no tail
        if (g >= n8) return;
        const float4 v0 = *(const float4*)(x + (size_t)g * 8);
        const float4 v1 = *(const float4*)(x + (size_t)g * 8 + 4);
        uint4 o;
        o.x = (unsigned)f2bf(v0.x) | ((unsigned)f2bf(v0.y) << 16);
        o.y = (unsigned)f2bf(v0.z) | ((unsigned)f2bf(v0.w) << 16);
        o.z = (unsigned)f2bf(v1.x) | ((unsigned)f2bf(v1.y) << 16);
        o.w = (unsigned)f2bf(v1.z) | ((unsigned)f2bf(v1.w) << 16);
        *(uint4*)(xb + (size_t)g * 8) = o;
        // int8 quant: 8 lanes per row (consecutive tids), 3-step shfl row-absmax
        const float v8[8] = {v0.x, v0.y, v0.z, v0.w, v1.x, v1.y, v1.z, v1.w};
        float mx = 0.f;
#pragma unroll
        for (int k = 0; k < 8; ++k) mx = fmaxf(mx, fabsf(v8[k]));
#pragma unroll
        for (int k = 1; k < 8; k <<= 1) mx = fmaxf(mx, __shfl_xor(mx, k, 64));
        const float rs = (mx > 0.f) ? 127.f / mx : 0.f;
        const int row = g >> 3;
        if ((g & 7) == 0) xs[row] = (mx > 0.f) ? mx / 127.f : 0.f;
        unsigned q0 = 0, q1 = 0;
#pragma unroll
        for (int k = 0; k < 4; ++k) q0 |= ((unsigned)__float2int_rn(v8[k] * rs) & 255u) << (8 * k);
#pragma unroll
        for (int k = 0; k < 4; ++k) q1 |= ((unsigned)__float2int_rn(v8[4 + k] * rs) & 255u) << (8 * k);
        *(uint2*)(xq + (size_t)row * 64 + (g & 7) * 8) = make_uint2(q0, q1);
    }
}

// ============ CSR pass 2: per-bucket finalize (r3-proven form, ~30us) ============
__global__ __launch_bounds__(256) void csr_finalize(const int* __restrict__ pairs,
                                                    const int* __restrict__ gcount,
                                                    int2* __restrict__ rowrange,
                                                    int* __restrict__ col, int N) {
    __shared__ int sp[CAP];
    __shared__ int h[64];
    __shared__ int tmp[64];
    __shared__ int cur[64];
    const int tid = threadIdx.x;
    const int b = blockIdx.x;
    const size_t base = (size_t)b * CAP;
    const int cnt = min(gcount[b], (int)CAP);

    for (int i = tid; i < cnt; i += 256) sp[i] = pairs[base + i];
    if (tid < 64) h[tid] = 0;
    __syncthreads();
    for (int i = tid; i < cnt; i += 256)
        atomicAdd(&h[(sp[i] >> 20) & 63], 1);
    __syncthreads();
    if (tid < 64) tmp[tid] = h[tid];
    __syncthreads();
    for (int off = 1; off < 64; off <<= 1) {
        int t = (tid >= off && tid < 64) ? tmp[tid - off] : 0;
        __syncthreads();
        if (tid < 64) tmp[tid] += t;
        __syncthreads();
    }
    if (tid < 64) {
        const int v = h[tid];
        const int excl = tmp[tid] - v;
        const int node = (b << 6) + tid;
        if (node < N) rowrange[node] = make_int2((int)base + excl, (int)base + excl + v);
        cur[tid] = excl;
    }
    __syncthreads();
    for (int i = tid; i < cnt; i += 256) {
        const int p = sp[i];
        const int slot = atomicAdd(&cur[(p >> 20) & 63], 1);
        col[base + slot] = p & 0xFFFFF;
    }
}

// ============ fused layer: int8 gather-mean + bf16 MFMA update ============
// 32 nodes/block, 128 threads (2 waves).
// Phase 1: 4 lanes/node, lane owns 16 dims = 16B of the 64B int8 row; the
//   4-lane group covers exactly ONE 64B line per edge (was two in bf16).
//   8-edge unroll -> 8 row-loads + 8 scale-loads outstanding. Dequant =
//   bfe+cvt+fma (3 VALU/elem); VALU had 4x headroom. Random footprint
//   6.4 MB -> much higher L2 hit. Mean accumulated in f32, written bf16.
// Phase 2: unchanged bf16 MFMA (self rows from xb, mean from LDS, bswp B).
// Epilogue: if outq, 16-lane shfl row-absmax -> int8+scale quantized copy of
//   the output (byte stores coalesce into 16B segments per instruction).
// out arrays MUST NOT alias inputs (random neighbor reads).
__global__ __launch_bounds__(128) void sage_fused_kernel(
        const unsigned short* __restrict__ xin,  // bf16 self rows
        const unsigned char* __restrict__ xq,    // int8 gather rows
        const float* __restrict__ xs,            // per-row scales
        const int* __restrict__ col, const int2* __restrict__ rowrange,
        const unsigned short* __restrict__ bswp, const float* __restrict__ bias,
        unsigned short* __restrict__ outb,       // bf16 out (may be null)
        unsigned char* __restrict__ outq,        // int8 out (may be null)
        float* __restrict__ outs,                // scale out (may be null)
        float* __restrict__ outf,                // f32 out (may be null)
        int N, int do_relu) {
    __shared__ __align__(16) unsigned short smean[32][72];

    const int tid = threadIdx.x;
    const int node0 = blockIdx.x * 32;
    const int lane = tid & 63;

    // ---- phase 1: int8 gather mean for node (tid>>2), 16 dims per lane ----
    {
        const int nl = tid >> 2;             // 0..31
        const int node = node0 + nl;
        const int c16 = (tid & 3) * 16;      // dim start
        float acc[16];
#pragma unroll
        for (int k = 0; k < 16; ++k) acc[k] = 0.f;
        float rd = 0.f;
        if (node < N) {
            const int2 rr = rowrange[node];
            const int beg = rr.x, end = rr.y;
            int i = beg;
            for (; i + 8 <= end; i += 8) {
                int s[8];
#pragma unroll
                for (int k = 0; k < 8; ++k) s[k] = col[i + k];
                uint4 v[8]; float sc[8];
#pragma unroll
                for (int k = 0; k < 8; ++k) {
                    v[k]  = *(const uint4*)(xq + (size_t)s[k] * 64 + c16);
                    sc[k] = xs[s[k]];
                }
#pragma unroll
                for (int k = 0; k < 8; ++k) { ACCQ4(acc, v[k], sc[k]) }
            }
            if (i + 4 <= end) {
                int s[4];
#pragma unroll
                for (int k = 0; k < 4; ++k) s[k] = col[i + k];
                uint4 v[4]; float sc[4];
#pragma unroll
                for (int k = 0; k < 4; ++k) {
                    v[k]  = *(const uint4*)(xq + (size_t)s[k] * 64 + c16);
                    sc[k] = xs[s[k]];
                }
#pragma unroll
                for (int k = 0; k < 4; ++k) { ACCQ4(acc, v[k], sc[k]) }
                i += 4;
            }
            for (; i < end; ++i) {
                const int s = col[i];
                const uint4 v = *(const uint4*)(xq + (size_t)s * 64 + c16);
                const float sc = xs[s];
                ACCQ4(acc, v, sc)
            }
            rd = 1.0f / fmaxf((float)(end - beg), 1.0f);
        }
        uint4 o0, o1;
        o0.x = (unsigned)f2bf(acc[0] * rd)  | ((unsigned)f2bf(acc[1] * rd) << 16);
        o0.y = (unsigned)f2bf(acc[2] * rd)  | ((unsigned)f2bf(acc[3] * rd) << 16);
        o0.z = (unsigned)f2bf(acc[4] * rd)  | ((unsigned)f2bf(acc[5] * rd) << 16);
        o0.w = (unsigned)f2bf(acc[6] * rd)  | ((unsigned)f2bf(acc[7] * rd) << 16);
        o1.x = (unsigned)f2bf(acc[8] * rd)  | ((unsigned)f2bf(acc[9] * rd) << 16);
        o1.y = (unsigned)f2bf(acc[10] * rd) | ((unsigned)f2bf(acc[11] * rd) << 16);
        o1.z = (unsigned)f2bf(acc[12] * rd) | ((unsigned)f2bf(acc[13] * rd) << 16);
        o1.w = (unsigned)f2bf(acc[14] * rd) | ((unsigned)f2bf(acc[15] * rd) << 16);
        *(uint4*)(&smean[nl][c16])     = o0;
        *(uint4*)(&smean[nl][c16 + 8]) = o1;
    }
    __syncthreads();

    // ---- phase 2: MFMA update (2 waves x 16 nodes) ----
    const int wave = tid >> 6;
    const int m    = lane & 15;
    const int quad = lane >> 4;
    const int nw0  = node0 + wave * 16;

    int arow = nw0 + m;
    if (arow >= N) arow = N - 1;             // clamp; stores are guarded
    const unsigned short* xr = xin + (size_t)arow * 64 + quad * 8;

    f32x4 acc[4];
#pragma unroll
    for (int t = 0; t < 4; ++t) {
        const float b = bias[t * 16 + m];
        acc[t] = (f32x4){b, b, b, b};
    }

#pragma unroll
    for (int s = 0; s < 4; ++s) {
        bf16x8 a;
        if (s < 2) a = *(const bf16x8*)(xr + s * 32);
        else       a = *(const bf16x8*)(&smean[wave * 16 + m][(s - 2) * 32 + quad * 8]);
#pragma unroll
        for (int t = 0; t < 4; ++t) {
            const bf16x8 bf = *(const bf16x8*)(bswp + (((s * 4 + t) * 64 + lane) << 3));
            acc[t] = __builtin_amdgcn_mfma_f32_16x16x32_bf16(a, bf, acc[t], 0, 0, 0);
        }
    }

    // relu in place, then stores. C/D: col = t*16+m, row(node) = nw0+quad*4+r
#pragma unroll
    for (int t = 0; t < 4; ++t) {
#pragma unroll
        for (int r = 0; r < 4; ++r) {
            float v = acc[t][r];
            if (do_relu) v = fmaxf(v, 0.f);
            acc[t][r] = v;
        }
    }
#pragma unroll
    for (int t = 0; t < 4; ++t) {
        const int colg = t * 16 + m;
#pragma unroll
        for (int r = 0; r < 4; ++r) {
            const int node = nw0 + quad * 4 + r;
            if (node < N) {
                if (outf) outf[(size_t)node * 64 + colg] = acc[t][r];
                if (outb) outb[(size_t)node * 64 + colg] = f2bf(acc[t][r]);
            }
        }
    }

    // ---- epilogue: int8+scale quantized output for the next layer's gather ----
    if (outq) {
#pragma unroll
        for (int r = 0; r < 4; ++r) {
            float mx = fmaxf(fmaxf(fabsf(acc[0][r]), fabsf(acc[1][r])),
                             fmaxf(fabsf(acc[2][r]), fabsf(acc[3][r])));
#pragma unroll
            for (int k = 1; k < 16; k <<= 1) mx = fmaxf(mx, __shfl_xor(mx, k, 64));
            const int node = nw0 + quad * 4 + r;
            const float rs = (mx > 0.f) ? 127.f / mx : 0.f;
            if (node < N) {
                if (m == 0) outs[node] = (mx > 0.f) ? mx / 127.f : 0.f;
#pragma unroll
                for (int t = 0; t < 4; ++t) {
                    const int q = __float2int_rn(acc[t][r] * rs);
                    outq[(size_t)node * 64 + t * 16 + m] = (unsigned char)q;
                }
            }
        }
    }
}

extern "C" void kernel_launch(void* const* d_in, const int* in_sizes, int n_in,
                              void* d_out, int out_size, void* d_ws, size_t ws_size,
                              hipStream_t stream) {
    const float* x   = (const float*)d_in[0];
    const int*   ei  = (const int*)d_in[1];
    const float* ws1 = (const float*)d_in[2];
    const float* wn1 = (const float*)d_in[3];
    const float* b1  = (const float*)d_in[4];
    const float* ws2 = (const float*)d_in[5];
    const float* wn2 = (const float*)d_in[6];
    const float* b2  = (const float*)d_in[7];
    const float* ws3 = (const float*)d_in[8];
    const float* wn3 = (const float*)d_in[9];
    const float* b3  = (const float*)d_in[10];

    const int N = in_sizes[0] / 64;   // 100000
    const int E = in_sizes[1] / 2;    // 1600000
    const int* src = ei;
    const int* dst = ei + E;
    const int NB = (N + BN - 1) / BN; // 1563 buckets of 64 nodes

    float* out = (float*)d_out;

    auto align256 = [](size_t v) { return (v + 255) / 256 * 256; };
    char* p = (char*)d_ws;
    int*  gcount   = (int*)p;  p += align256((size_t)NB * 4);
    int*  pairs    = (int*)p;  p += align256((size_t)NB * CAP * 4);
    int*  col      = (int*)p;  p += align256((size_t)NB * CAP * 4);
    int2* rowrange = (int2*)p; p += align256((size_t)N * 8);
    unsigned short* xb  = (unsigned short*)p; p += align256((size_t)N * 64 * 2);
    unsigned short* xb2 = (unsigned short*)p; p += align256((size_t)N * 64 * 2);
    unsigned char*  xq  = (unsigned char*)p;  p += align256((size_t)N * 64);
    unsigned char*  xq2 = (unsigned char*)p;  p += align256((size_t)N * 64);
    float* xs  = (float*)p; p += align256((size_t)N * 4);
    float* xs2 = (float*)p; p += align256((size_t)N * 4);
    unsigned short* bw  = (unsigned short*)p; p += align256(3 * 8192 * 2);

    const int n8 = N * 64 / 8;                            // 800000
    const int merged_blocks = PB + 96 + (n8 + 255) / 256; // 512 + 96 + 3125
    const int fused_blocks = (N + 31) / 32;               // 3125

    // ---- CSR pass 1 + weight packs + bf16/int8 shadows, one launch ----
    hipMemsetAsync(gcount, 0, (size_t)NB * 4, stream);
    build_and_prep<<<merged_blocks, 256, 0, stream>>>(src, dst, gcount, pairs, E, NB,
                                                      x, xb, xq, xs, n8,
                                                      ws1, wn1, ws2, wn2, ws3, wn3, bw);
    // ---- CSR pass 2 ----
    csr_finalize<<<NB, 256, 0, stream>>>(pairs, gcount, rowrange, col, N);

    // ---- 3 fused layers (ping-pong bf16 + int8 shadows) ----
    sage_fused_kernel<<<fused_blocks, 128, 0, stream>>>(xb,  xq,  xs,  col, rowrange, bw,         b1, xb2, xq2, xs2, nullptr, N, 1);
    sage_fused_kernel<<<fused_blocks, 128, 0, stream>>>(xb2, xq2, xs2, col, rowrange, bw + 8192,  b2, xb,  xq,  xs,  nullptr, N, 1);
    sage_fused_kernel<<<fused_blocks, 128, 0, stream>>>(xb,  xq,  xs,  col, rowrange, bw + 16384, b3, nullptr, nullptr, nullptr, out, N, 0);
}